// Round 7
// baseline (405.713 us; speedup 1.0000x reference)
//
#include <hip/hip_runtime.h>

#define LTC_B 512
#define LTC_H 512
#define LTC_I 256

static constexpr float kL2E = 1.4426950408889634f;  // log2(e)

typedef _Float16 half2v __attribute__((ext_vector_type(2)));
typedef __fp16   fp16x2 __attribute__((ext_vector_type(2)));

// Pre-transformed weight pair (2 j's for one h), 16B, all f16:
// t = a*v + c (log2 domain), sig = 1/(1+2^t), n += wz*sig, d += wd*sig.
struct alignas(16) HPair { _Float16 a0, a1, c0, c1, wz0, wz1, wd0, wd1; };

// slab unit ((ht*(K/2) + jp)*64 + hh) holds j=2jp,2jp+1 for h=ht*64+hh.
// A wave's 32 pairs load as 32 coalesced global_load_dwordx4 (1KB rows).
template<int K>
__global__ void ltc_prep(const float* __restrict__ mu, const float* __restrict__ sigma,
                         const float* __restrict__ W, const float* __restrict__ erev,
                         HPair* __restrict__ slab) {
    const int t = blockIdx.x * 256 + threadIdx.x;   // one thread per 16B unit
    if (t >= K * 256) return;
    const int hh   = t & 63;
    const int rest = t >> 6;
    const int jp   = rest & (K / 2 - 1);
    const int ht   = rest / (K / 2);
    const int h    = ht * 64 + hh;
    const int g0   = (2 * jp) * LTC_H + h;
    const int g1   = g0 + LTC_H;
    HPair o;
    o.a0 = (_Float16)(-sigma[g0] * kL2E);
    o.a1 = (_Float16)(-sigma[g1] * kL2E);
    o.c0 = (_Float16)(mu[g0] * sigma[g0] * kL2E);
    o.c1 = (_Float16)(mu[g1] * sigma[g1] * kL2E);
    o.wz0 = (_Float16)(W[g0] * erev[g0]);
    o.wz1 = (_Float16)(W[g1] * erev[g1]);
    o.wd0 = (_Float16)(W[g0]);
    o.wd1 = (_Float16)(W[g1]);
    slab[t] = o;
}

// Weight-stationary pass. Block = 4 waves; wave owns 64 j's (32 pairs) held in
// VGPRs (f16 -> f32 converted ONCE at load), lane = h within the ht tile.
// Block loops over 8 batch rows; per row: compute partial (n,d) over the
// wave's j-slice, tiny 4-wave LDS combine, one wave stores the K-half partial.
// No global_load_lds, no chunk barriers -- the only syncs are 8 plain joins.
// Grid (8 ht, K/256 ks, 64 bt) -> 1024 (recur) / 512 (sensory) blocks.
template<int K>
__global__ __launch_bounds__(256, 2)
void ltc_wpass(const float* __restrict__ vsrc,   // B x K
               const HPair* __restrict__ slab,   // [8][K/2][64]
               float2* __restrict__ pout)        // [K/256][B][H] (n,d)
{
    __shared__ float2 cb[2][4][64];              // ping-pong combine buffer, 4KB
    const int lane = threadIdx.x & 63;
    const int wave = threadIdx.x >> 6;           // 0..3
    const int ht   = blockIdx.x;                 // 0..7
    const int ks   = blockIdx.y;                 // 0..K/256-1
    const int jb   = (ks * 4 + wave) * 64;       // wave's j-base
    const int b0   = blockIdx.z * 8;
    float2* __restrict__ po = pout + (size_t)ks * (LTC_B * LTC_H);

    // --- load the wave's weights into registers, convert f16->f32 once ---
    const HPair* wsl = slab + ((size_t)ht * (K / 2) + (jb >> 1)) * 64 + lane;
    float  wa0[32], wa1[32], wc0[32], wc1[32];   // 128 VGPR
    half2v wz[32], wd[32];                       // 64 VGPR
    #pragma unroll
    for (int p = 0; p < 32; ++p) {
        const HPair hp = wsl[p * 64];            // global_load_dwordx4, coalesced
        wa0[p] = (float)hp.a0;  wa1[p] = (float)hp.a1;
        wc0[p] = (float)hp.c0;  wc1[p] = (float)hp.c1;
        wz[p]  = half2v{hp.wz0, hp.wz1};
        wd[p]  = half2v{hp.wd0, hp.wd1};
    }

    for (int ib = 0; ib < 8; ++ib) {
        const int b = b0 + ib;
        const float* __restrict__ vb = vsrc + (size_t)b * K + jb;  // uniform -> s_load
        float na = 0.f, da = 0.f;
        #pragma unroll
        for (int p = 0; p < 32; ++p) {
            const float vj0 = vb[2 * p];         // scalar broadcast
            const float vj1 = vb[2 * p + 1];
            const float t0 = fmaf(wa0[p], vj0, wc0[p]);
            const float t1 = fmaf(wa1[p], vj1, wc1[p]);
            const float e0 = __builtin_amdgcn_exp2f(t0);
            const float e1 = __builtin_amdgcn_exp2f(t1);
            const float d0 = 1.0f + e0;
            const float d1 = 1.0f + e1;
            const float rr = __builtin_amdgcn_rcpf(d0 * d1);  // 1 rcp / 2 sig
            const fp16x2 spr = __builtin_amdgcn_cvt_pkrtz(rr * d1, rr * d0);
            const half2v sp  = __builtin_bit_cast(half2v, spr);
            na = __builtin_amdgcn_fdot2(wz[p], sp, na, false);
            da = __builtin_amdgcn_fdot2(wd[p], sp, da, false);
        }
        // --- 4-wave combine: plain join, no DMA drain behind this barrier ---
        cb[ib & 1][wave][lane] = float2{na, da};
        __syncthreads();
        if (wave == (ib & 3)) {                  // rotate the storing wave
            const float2 q0 = cb[ib & 1][0][lane];
            const float2 q1 = cb[ib & 1][1][lane];
            const float2 q2 = cb[ib & 1][2][lane];
            const float2 q3 = cb[ib & 1][3][lane];
            float2 r;
            r.x = (q0.x + q1.x) + (q2.x + q3.x);
            r.y = (q0.y + q1.y) + (q2.y + q3.y);
            po[(size_t)b * LTC_H + ht * 64 + lane] = r;
        }
    }
}

// Elementwise epilogue: v' = (cm*v + gleak*vleak + n) / (cm + gleak + d + eps)
__global__ __launch_bounds__(256)
void ltc_fin(const float* __restrict__ vpre, const float2* __restrict__ pnd,
             const float2* __restrict__ snd,
             const float* __restrict__ vleak, const float* __restrict__ gleak,
             const float* __restrict__ cm, float* __restrict__ vout)
{
    const int i = blockIdx.x * 256 + threadIdx.x;    // grid = 1024 blocks
    const int h = i & (LTC_H - 1);
    const float2 p0 = pnd[i];
    const float2 p1 = pnd[LTC_B * LTC_H + i];
    const float2 s  = snd[i];
    const float gl = gleak[h], c = cm[h];
    const float num = fmaf(c, vpre[i], gl * vleak[h]) + p0.x + p1.x + s.x;
    const float den = c + gl + p0.y + p1.y + s.y;
    vout[i] = num * __builtin_amdgcn_rcpf(den + 1e-8f);
}

extern "C" void kernel_launch(void* const* d_in, const int* in_sizes, int n_in,
                              void* d_out, int out_size, void* d_ws, size_t ws_size,
                              hipStream_t stream) {
    const float* inputs = (const float*)d_in[0];   // B x I
    const float* state  = (const float*)d_in[1];   // B x H
    const float* smu    = (const float*)d_in[2];   // I x H
    const float* ssig   = (const float*)d_in[3];
    const float* sW     = (const float*)d_in[4];
    const float* serev  = (const float*)d_in[5];
    const float* mu     = (const float*)d_in[6];   // H x H
    const float* sig    = (const float*)d_in[7];
    const float* W      = (const float*)d_in[8];
    const float* erev   = (const float*)d_in[9];
    const float* vleak  = (const float*)d_in[10];  // H
    const float* gleak  = (const float*)d_in[11];
    const float* cm     = (const float*)d_in[12];

    float* out  = (float*)d_out;                   // B x H
    char*  ws   = (char*)d_ws;
    const size_t MB = 1048576;
    float2* sND   = (float2*)(ws);                 // 2MB  [B][H]
    float2* pND   = (float2*)(ws + 2 * MB);        // 4MB  [2][B][H]
    float*  vA    = (float*) (ws + 6 * MB);        // 1MB
    float*  vB    = (float*) (ws + 7 * MB);        // 1MB
    HPair*  rslab = (HPair*) (ws + 8 * MB);        // 2MB  (H x H)
    HPair*  sslab = (HPair*) (ws + 10 * MB);       // 1MB  (I x H)
    // total ws use: 11 MB (<= 12 MB proven safe in earlier rounds)

    // Prep: transform + pair-pack weights once per launch.
    ltc_prep<LTC_H><<<LTC_H * 256 / 256, 256, 0, stream>>>(mu, sig, W, erev, rslab);
    ltc_prep<LTC_I><<<LTC_I * 256 / 256, 256, 0, stream>>>(smu, ssig, sW, serev, sslab);

    // Sensory pass: one ks slice covers all 256 j -> sND directly.
    ltc_wpass<LTC_I><<<dim3(8, 1, 64), 256, 0, stream>>>(inputs, sslab, sND);

    // 6 unfolds: pass (partials) + finalize (leak + divide).
    const float* vpre = state;
    float* vtgt[6] = {vA, vB, vA, vB, vA, out};
    for (int s = 0; s < 6; ++s) {
        ltc_wpass<LTC_H><<<dim3(8, 2, 64), 256, 0, stream>>>(vpre, rslab, pND);
        ltc_fin<<<LTC_B * LTC_H / 256, 256, 0, stream>>>(
            vpre, pND, sND, vleak, gleak, cm, vtgt[s]);
        vpre = vtgt[s];
    }
}